// Round 3
// baseline (408.177 us; speedup 1.0000x reference)
//
#include <hip/hip_runtime.h>
#include <hip/hip_bf16.h>

#define BD 8
#define LD 2048
#define DD 256
#define TI 16
#define JC 32
#define WPAD 20
#define APAD 36
#define WPD 260

// ---------------- Kernel 1: temporal encoding + per-row params ----------------
__global__ __launch_bounds__(256) void k_prep(
    const int* __restrict__ etype, const float* __restrict__ etime,
    const float* __restrict__ embw, const float* __restrict__ gatew,
    const float* __restrict__ gateb, const float* __restrict__ kerw,
    const float* __restrict__ kerb,
    float* __restrict__ enc, float* __restrict__ t_arr,
    float* __restrict__ invls2, float* __restrict__ l_arr,
    float* __restrict__ invs)
{
  int bl = blockIdx.x;
  int d = threadIdx.x;
  float t = etime[bl];
  int ty = etype[bl];
  float te = embw[ty * DD + d] * 16.0f;   // * sqrt(256)
  // pos_vec = 10000^(2d/256)  ->  t * exp(-d * 2*ln(1e4)/256)
  float freq = __expf(-0.07195578416f * (float)d);
  float arg = t * freq;
  float e = ((d & 1) == 0) ? sinf(arg) : cosf(arg);
  enc[(size_t)bl * DD + d] = e;
  float p1 = te * kerw[d];
  float p2 = te * gatew[d];
  float p3 = te * gatew[DD + d];
  #pragma unroll
  for (int off = 32; off > 0; off >>= 1) {
    p1 += __shfl_xor(p1, off);
    p2 += __shfl_xor(p2, off);
    p3 += __shfl_xor(p3, off);
  }
  __shared__ float red[4][3];
  int lane = d & 63, wv = d >> 6;
  if (lane == 0) { red[wv][0] = p1; red[wv][1] = p2; red[wv][2] = p3; }
  __syncthreads();
  if (d == 0) {
    float s1 = red[0][0] + red[1][0] + red[2][0] + red[3][0] + kerb[0];
    float s2 = red[0][1] + red[1][1] + red[2][1] + red[3][1] + gateb[0];
    float s3 = red[0][2] + red[1][2] + red[2][2] + red[3][2] + gateb[1];
    // ls = softplus(0.2*x)/0.2
    float z = 0.2f * s1;
    float sp = (z > 15.0f) ? z : log1pf(__expf(z));
    float ls = 5.0f * sp;
    invls2[bl] = 1.0f / (ls * ls);
    l_arr[bl] = 1.0f / (1.0f + __expf(-s2));
    float s = 1.0f / (1.0f + __expf(-s3));
    invs[bl] = 1.0f / s;
    t_arr[bl] = t;
  }
}

// ---------------- Kernel 2: causal gated attention + layernorm ----------------
// block = 256 thr (4 waves); block tile = 16 rows; wave handles rows i0+4*wv+{0..3},
// lane covers dims 4*lane..4*lane+3. j processed in chunks of 32 staged in LDS.
__global__ __launch_bounds__(256) void k_attn(
    const float* __restrict__ enc, const float* __restrict__ t_arr,
    const float* __restrict__ ils_a, const float* __restrict__ l_a,
    const float* __restrict__ is_a, const float* __restrict__ gamma,
    const float* __restrict__ beta, float* __restrict__ hidden)
{
  __shared__ float enc_s[JC * DD];     // 32 KB
  __shared__ float w_s[JC * WPAD];
  const int tid = threadIdx.x;
  const int lane = tid & 63, wv = tid >> 6;
  const int b = blockIdx.y;
  const int i0 = ((int)gridDim.x - 1 - (int)blockIdx.x) * TI;  // big blocks first
  const int base = b * LD;
  const int jj = tid & 31;
  const int roff = (lane >= 32) ? 2 : 0;
  const int rA = i0 + 4 * wv + roff;   // this thread generates weights for rows rA,rA+1
  const int rB = rA + 1;
  const float tiA = t_arr[base + rA], tiB = t_arr[base + rB];
  const float ilA = ils_a[base + rA], ilB = ils_a[base + rB];
  const float llA = l_a[base + rA],  llB = l_a[base + rB];
  const float isA = is_a[base + rA], isB = is_a[base + rB];
  float acc[4][4] = {{0.0f}};
  float den[4] = {0.0f, 0.0f, 0.0f, 0.0f};
  const int nch = (i0 + TI + JC - 1) / JC;
  const float4* __restrict__ encb = (const float4*)(enc + (size_t)base * DD);
  for (int ch = 0; ch < nch; ++ch) {
    const int jc = ch * JC;
    // stage enc tile [32][256] fp32
    {
      const float4* src = encb + (size_t)jc * (DD / 4);
      float4* dst = (float4*)enc_s;
      #pragma unroll
      for (int it = 0; it < 8; ++it) dst[it * 256 + tid] = src[it * 256 + tid];
    }
    // softmax weights w = exp(score), score in (0,1.5] -> no max-subtraction needed
    {
      const float tj = t_arr[base + jc + jj];
      float dtA = fabsf(tiA - tj);
      float skA = __expf(-dtA * dtA * ilA);
      float rgA = __builtin_amdgcn_rcpf(__expf(2.0f * (dtA * 0.005f - llA) * isA) + 1.0f);
      float wA = __expf(skA * (1.5f - rgA));      // gate = 1+0.5*tanh = 1.5 - 1/(e^{2z}+1)
      wA = (jc + jj <= rA) ? wA : 0.0f;           // causal mask
      w_s[jj * WPAD + 4 * wv + roff] = wA;
      float dtB = fabsf(tiB - tj);
      float skB = __expf(-dtB * dtB * ilB);
      float rgB = __builtin_amdgcn_rcpf(__expf(2.0f * (dtB * 0.005f - llB) * isB) + 1.0f);
      float wB = __expf(skB * (1.5f - rgB));
      wB = (jc + jj <= rB) ? wB : 0.0f;
      w_s[jj * WPAD + 4 * wv + roff + 1] = wB;
    }
    __syncthreads();
    if (lane < 32) {   // denominator partials (per-lane over jj, reduced at end)
      float4 w4 = *(const float4*)&w_s[lane * WPAD + 4 * wv];
      den[0] += w4.x; den[1] += w4.y; den[2] += w4.z; den[3] += w4.w;
    }
    #pragma unroll 8
    for (int j2 = 0; j2 < JC; ++j2) {
      const float4 w4 = *(const float4*)&w_s[j2 * WPAD + 4 * wv];       // broadcast
      const float4 e4 = *(const float4*)&enc_s[j2 * DD + 4 * lane];     // conflict-free
      acc[0][0] += w4.x * e4.x; acc[0][1] += w4.x * e4.y;
      acc[0][2] += w4.x * e4.z; acc[0][3] += w4.x * e4.w;
      acc[1][0] += w4.y * e4.x; acc[1][1] += w4.y * e4.y;
      acc[1][2] += w4.y * e4.z; acc[1][3] += w4.y * e4.w;
      acc[2][0] += w4.z * e4.x; acc[2][1] += w4.z * e4.y;
      acc[2][2] += w4.z * e4.z; acc[2][3] += w4.z * e4.w;
      acc[3][0] += w4.w * e4.x; acc[3][1] += w4.w * e4.y;
      acc[3][2] += w4.w * e4.z; acc[3][3] += w4.w * e4.w;
    }
    __syncthreads();
  }
  #pragma unroll
  for (int k = 0; k < 4; ++k) {
    #pragma unroll
    for (int off = 32; off > 0; off >>= 1) den[k] += __shfl_xor(den[k], off);
  }
  float4 g4 = *(const float4*)(gamma + 4 * lane);
  float4 c4 = *(const float4*)(beta + 4 * lane);
  #pragma unroll
  for (int k = 0; k < 4; ++k) {
    float rd = 1.0f / den[k];
    float h0 = acc[k][0] * rd, h1 = acc[k][1] * rd;
    float h2 = acc[k][2] * rd, h3 = acc[k][3] * rd;
    float sm = h0 + h1 + h2 + h3;
    float sq = h0 * h0 + h1 * h1 + h2 * h2 + h3 * h3;
    #pragma unroll
    for (int off = 32; off > 0; off >>= 1) {
      sm += __shfl_xor(sm, off);
      sq += __shfl_xor(sq, off);
    }
    float mean = sm * (1.0f / 256.0f);
    float var = sq * (1.0f / 256.0f) - mean * mean;   // population var (ddof=0)
    float rstd = rsqrtf(var + 1e-6f);
    int i = i0 + 4 * wv + k;
    float4 o;
    o.x = (h0 - mean) * rstd * g4.x + c4.x;
    o.y = (h1 - mean) * rstd * g4.y + c4.y;
    o.z = (h2 - mean) * rstd * g4.z + c4.z;
    o.w = (h3 - mean) * rstd * g4.w + c4.w;
    *(float4*)&hidden[(size_t)(base + i) * DD + 4 * lane] = o;
  }
}

// ---------------- Kernel 3: generator (concat-K GEMM + fused head) ----------------
// X[r,c] = sum_k noise[r,k]*Wn[c,k] + sum_k hidden[r,k]*Wi[c,k]  (K=512 concat)
// out[r] = softplus(sum_c relu(X[r,c])*wo[c] + bo)
// block = 256 thr; tile 32 rows x 256 cols; wave wv: rows wv*8..wv*8+7, lane: cols 4*lane..
__global__ __launch_bounds__(256) void k_gen(
    const float* __restrict__ noise, const float* __restrict__ hidden,
    const float* __restrict__ wnoise, const float* __restrict__ winput,
    const float* __restrict__ wout, const float* __restrict__ bout,
    float* __restrict__ out)
{
  __shared__ float A_s[32 * APAD];   // [k][row], padded
  __shared__ float W_s[32 * WPD];    // [k][col], padded
  const int tid = threadIdx.x;
  const int lane = tid & 63, wv = tid >> 6;
  const int r0 = blockIdx.x * 32;
  float acc[8][4] = {{0.0f}};
  #pragma unroll 1
  for (int ch = 0; ch < 16; ++ch) {
    const int kc = ch * 32;
    const bool first = (kc < 256);
    const int k0 = first ? kc : (kc - 256);
    {
      const int row = tid >> 3;
      const int k4 = (tid & 7) * 4;
      const float* A = first ? noise : hidden;
      float4 f = *(const float4*)(A + (size_t)(r0 + row) * DD + k0 + k4);
      A_s[(k4 + 0) * APAD + row] = f.x;
      A_s[(k4 + 1) * APAD + row] = f.y;
      A_s[(k4 + 2) * APAD + row] = f.z;
      A_s[(k4 + 3) * APAD + row] = f.w;
    }
    {
      const float* W = first ? wnoise : winput;
      const int k4 = (tid & 7) * 4;
      const int cb = tid >> 3;
      #pragma unroll
      for (int it = 0; it < 8; ++it) {
        int c = it * 32 + cb;
        float4 f = *(const float4*)(W + (size_t)c * DD + k0 + k4);
        W_s[(k4 + 0) * WPD + c] = f.x;
        W_s[(k4 + 1) * WPD + c] = f.y;
        W_s[(k4 + 2) * WPD + c] = f.z;
        W_s[(k4 + 3) * WPD + c] = f.w;
      }
    }
    __syncthreads();
    #pragma unroll 8
    for (int k = 0; k < 32; ++k) {
      const float4 a0 = *(const float4*)&A_s[k * APAD + wv * 8];      // broadcast
      const float4 a1 = *(const float4*)&A_s[k * APAD + wv * 8 + 4];  // broadcast
      const float4 wl = *(const float4*)&W_s[k * WPD + 4 * lane];     // conflict-free
      acc[0][0] += a0.x * wl.x; acc[0][1] += a0.x * wl.y; acc[0][2] += a0.x * wl.z; acc[0][3] += a0.x * wl.w;
      acc[1][0] += a0.y * wl.x; acc[1][1] += a0.y * wl.y; acc[1][2] += a0.y * wl.z; acc[1][3] += a0.y * wl.w;
      acc[2][0] += a0.z * wl.x; acc[2][1] += a0.z * wl.y; acc[2][2] += a0.z * wl.z; acc[2][3] += a0.z * wl.w;
      acc[3][0] += a0.w * wl.x; acc[3][1] += a0.w * wl.y; acc[3][2] += a0.w * wl.z; acc[3][3] += a0.w * wl.w;
      acc[4][0] += a1.x * wl.x; acc[4][1] += a1.x * wl.y; acc[4][2] += a1.x * wl.z; acc[4][3] += a1.x * wl.w;
      acc[5][0] += a1.y * wl.x; acc[5][1] += a1.y * wl.y; acc[5][2] += a1.y * wl.z; acc[5][3] += a1.y * wl.w;
      acc[6][0] += a1.z * wl.x; acc[6][1] += a1.z * wl.y; acc[6][2] += a1.z * wl.z; acc[6][3] += a1.z * wl.w;
      acc[7][0] += a1.w * wl.x; acc[7][1] += a1.w * wl.y; acc[7][2] += a1.w * wl.z; acc[7][3] += a1.w * wl.w;
    }
    __syncthreads();
  }
  float4 wo4 = *(const float4*)(wout + 4 * lane);
  float bo = bout[0];
  float p[8];
  #pragma unroll
  for (int r = 0; r < 8; ++r) {
    p[r] = fmaxf(acc[r][0], 0.0f) * wo4.x + fmaxf(acc[r][1], 0.0f) * wo4.y
         + fmaxf(acc[r][2], 0.0f) * wo4.z + fmaxf(acc[r][3], 0.0f) * wo4.w;
    #pragma unroll
    for (int off = 32; off > 0; off >>= 1) p[r] += __shfl_xor(p[r], off);
  }
  if (lane == 0) {
    #pragma unroll
    for (int r = 0; r < 8; ++r) {
      float x = p[r] + bo;
      float sp = (x > 15.0f) ? x : log1pf(__expf(x));
      out[r0 + wv * 8 + r] = sp;
    }
  }
}

extern "C" void kernel_launch(void* const* d_in, const int* in_sizes, int n_in,
                              void* d_out, int out_size, void* d_ws, size_t ws_size,
                              hipStream_t stream) {
  const int*   etype = (const int*)d_in[0];
  const float* etime = (const float*)d_in[1];
  const float* embw  = (const float*)d_in[2];
  const float* gatew = (const float*)d_in[3];
  const float* gateb = (const float*)d_in[4];
  const float* kerw  = (const float*)d_in[5];
  const float* kerb  = (const float*)d_in[6];
  const float* gamma = (const float*)d_in[7];
  const float* beta  = (const float*)d_in[8];
  const float* wi    = (const float*)d_in[9];   // gen_input_w
  const float* wn    = (const float*)d_in[10];  // gen_noise_w
  const float* wo    = (const float*)d_in[11];  // gen_out_w
  const float* bo    = (const float*)d_in[12];  // gen_out_b
  const float* noise = (const float*)d_in[13];
  float* out = (float*)d_out;

  float* ws     = (float*)d_ws;
  float* enc    = ws;                    // B*L*D fp32 = 16 MB
  float* hidden = ws + 4194304;          // B*L*D fp32 = 16 MB
  float* t_arr  = ws + 8388608;          // B*L
  float* invls2 = t_arr + 16384;
  float* l_arr  = invls2 + 16384;
  float* invs   = l_arr + 16384;

  k_prep<<<BD * LD, 256, 0, stream>>>(etype, etime, embw, gatew, gateb, kerw, kerb,
                                      enc, t_arr, invls2, l_arr, invs);
  k_attn<<<dim3(LD / TI, BD), 256, 0, stream>>>(enc, t_arr, invls2, l_arr, invs,
                                                gamma, beta, hidden);
  k_gen<<<(BD * LD) / 32, 256, 0, stream>>>(noise, hidden, wn, wi, wo, bo, out);
}

// Round 4
// 238.354 us; speedup vs baseline: 1.7125x; 1.7125x over previous
//
#include <hip/hip_runtime.h>
#include <hip/hip_bf16.h>

#define BD 8
#define LD 2048
#define DD 256

typedef unsigned short ushort_t;
typedef __attribute__((ext_vector_type(8))) short short8;
typedef __attribute__((ext_vector_type(4))) float floatx4;

__device__ __forceinline__ float bfu2f(ushort_t u) {
  union { unsigned int i; float f; } v; v.i = ((unsigned int)u) << 16; return v.f;
}
__device__ __forceinline__ ushort_t f2bfu(float x) {
  __hip_bfloat16 h = __float2bfloat16(x);
  return *reinterpret_cast<ushort_t*>(&h);
}

// ---------------- Kernel A: per-row params (t, inv ls^2, gate l, 1/s) ----------------
__global__ __launch_bounds__(256) void k_prep_params(
    const int* __restrict__ etype, const float* __restrict__ etime,
    const float* __restrict__ embw, const float* __restrict__ gatew,
    const float* __restrict__ gateb, const float* __restrict__ kerw,
    const float* __restrict__ kerb,
    float* __restrict__ t_arr, float* __restrict__ invls2,
    float* __restrict__ l_arr, float* __restrict__ invs)
{
  int bl = blockIdx.x;
  int d = threadIdx.x;
  float t = etime[bl];
  int ty = etype[bl];
  float te = embw[ty * DD + d] * 16.0f;   // * sqrt(256)
  float p1 = te * kerw[d];
  float p2 = te * gatew[d];
  float p3 = te * gatew[DD + d];
  #pragma unroll
  for (int off = 32; off > 0; off >>= 1) {
    p1 += __shfl_xor(p1, off);
    p2 += __shfl_xor(p2, off);
    p3 += __shfl_xor(p3, off);
  }
  __shared__ float red[4][3];
  int lane = d & 63, wv = d >> 6;
  if (lane == 0) { red[wv][0] = p1; red[wv][1] = p2; red[wv][2] = p3; }
  __syncthreads();
  if (d == 0) {
    float s1 = red[0][0] + red[1][0] + red[2][0] + red[3][0] + kerb[0];
    float s2 = red[0][1] + red[1][1] + red[2][1] + red[3][1] + gateb[0];
    float s3 = red[0][2] + red[1][2] + red[2][2] + red[3][2] + gateb[1];
    float z = 0.2f * s1;
    float sp = (z > 15.0f) ? z : log1pf(__expf(z));
    float ls = 5.0f * sp;                  // softplus(0.2x)/0.2
    invls2[bl] = 1.0f / (ls * ls);
    l_arr[bl] = 1.0f / (1.0f + __expf(-s2));
    float s = 1.0f / (1.0f + __expf(-s3));
    invs[bl] = 1.0f / s;
    t_arr[bl] = t;
  }
}

// ---------------- Kernel B: temporal encoding, bf16, B-fragment-native layout ----------------
// enc_bf[b][ch][d][jj]  (ch = j>>5, jj = j&31): 16B at (d*32 + kg*8) is one B-frag slice.
__global__ __launch_bounds__(256) void k_prep_enc(
    const float* __restrict__ t_arr, ushort_t* __restrict__ enc_bf)
{
  int bk = blockIdx.x;            // 0..511 : b = bk>>6, ch = bk&63
  int d = threadIdx.x;
  __shared__ float ts[32];
  if (d < 32) ts[d] = t_arr[(bk >> 6) * LD + (bk & 63) * 32 + d];
  __syncthreads();
  float freq = __expf(-0.07195578416f * (float)d);   // 10000^(-2d/256)
  unsigned int pk[16];
  #pragma unroll
  for (int j2 = 0; j2 < 16; ++j2) {
    float a0 = ts[2 * j2] * freq;
    float a1 = ts[2 * j2 + 1] * freq;
    float v0 = (d & 1) ? cosf(a0) : sinf(a0);
    float v1 = (d & 1) ? cosf(a1) : sinf(a1);
    pk[j2] = (unsigned int)f2bfu(v0) | ((unsigned int)f2bfu(v1) << 16);
  }
  uint4* dst = (uint4*)(enc_bf + ((size_t)bk * 256 + d) * 32);
  dst[0] = make_uint4(pk[0], pk[1], pk[2], pk[3]);
  dst[1] = make_uint4(pk[4], pk[5], pk[6], pk[7]);
  dst[2] = make_uint4(pk[8], pk[9], pk[10], pk[11]);
  dst[3] = make_uint4(pk[12], pk[13], pk[14], pk[15]);
}

// ---------------- Kernel C: cast noise + concat weights to bf16 ----------------
__global__ __launch_bounds__(256) void k_cast(
    const float* __restrict__ noise, const float* __restrict__ wn,
    const float* __restrict__ wi, ushort_t* __restrict__ noise_bf,
    ushort_t* __restrict__ wcat)
{
  int idx = blockIdx.x * 256 + threadIdx.x;     // float4 index
  if (idx < 1048576) {
    float4 f = ((const float4*)noise)[idx];
    ushort4 u;
    u.x = f2bfu(f.x); u.y = f2bfu(f.y); u.z = f2bfu(f.z); u.w = f2bfu(f.w);
    *(ushort4*)(noise_bf + (size_t)idx * 4) = u;
  } else {
    int p = idx - 1048576;                      // 0..32767
    int c = p >> 7;
    int k = (p & 127) * 4;
    const float* src = (k < 256) ? (wn + c * 256 + k) : (wi + c * 256 + (k - 256));
    float4 f = *(const float4*)src;
    ushort4 u;
    u.x = f2bfu(f.x); u.y = f2bfu(f.y); u.z = f2bfu(f.z); u.w = f2bfu(f.w);
    *(ushort4*)(wcat + (size_t)c * 512 + k) = u;
  }
}

// ---------------- Kernel D: MFMA causal gated attention + layernorm ----------------
// 4 waves/block, each wave = one independent 16-row M-tile x 256 dims.
// A-frag (weights) computed analytically in registers; B-frags read from enc_bf via L1.
// Tile pairing {2kb, 2kb+1, 126-2kb, 127-2kb} balances triangular work.
__global__ __launch_bounds__(256) void k_attn(
    const ushort_t* __restrict__ enc_bf, const float* __restrict__ t_arr,
    const float* __restrict__ ils_a, const float* __restrict__ l_a,
    const float* __restrict__ is_a, const float* __restrict__ gamma,
    const float* __restrict__ beta, ushort_t* __restrict__ hidden_bf)
{
  const int tid = threadIdx.x;
  const int lane = tid & 63, wv = tid >> 6;
  const int bk = blockIdx.x;
  const int b = bk >> 5, kb = bk & 31;
  const int tl = (wv == 0) ? 2 * kb : (wv == 1) ? 2 * kb + 1
               : (wv == 2) ? 126 - 2 * kb : 127 - 2 * kb;
  const int base = b * LD;
  const int m = lane & 15, kg = lane >> 4;
  const int i = tl * 16 + m;                 // this lane's A-row
  const float ti = t_arr[base + i];
  const float il = ils_a[base + i];
  const float ll = l_a[base + i];
  const float is2 = 2.0f * is_a[base + i];
  floatx4 acc[16];
  #pragma unroll
  for (int nt = 0; nt < 16; ++nt) acc[nt] = (floatx4){0.f, 0.f, 0.f, 0.f};
  float den = 0.0f;
  const int nch = tl / 2 + 1;
  const ushort_t* __restrict__ encB = enc_bf + (size_t)(b * 64) * 8192;
  const int boff = m * 32 + kg * 8;          // B-frag lane offset within a chunk
  for (int ch = 0; ch < nch; ++ch) {
    const int j0 = ch * 32 + kg * 8;
    float4 tja = *(const float4*)(t_arr + base + j0);
    float4 tjb = *(const float4*)(t_arr + base + j0 + 4);
    float tj[8] = {tja.x, tja.y, tja.z, tja.w, tjb.x, tjb.y, tjb.z, tjb.w};
    short8 af;
    #pragma unroll
    for (int v = 0; v < 8; ++v) {
      float dt = fabsf(ti - tj[v]);
      float sk = __expf(-dt * dt * il);
      float rg = __builtin_amdgcn_rcpf(__expf((dt * 0.005f - ll) * is2) + 1.0f);
      float w = __expf(sk * (1.5f - rg));    // exp(sk * gate), gate = 1.5 - 1/(e^{2z}+1)
      w = (j0 + v <= i) ? w : 0.0f;          // causal mask
      ushort_t ub = f2bfu(w);
      af[v] = (short)ub;
      den += bfu2f(ub);                      // denominator consistent with bf16 numerator
    }
    const ushort_t* bp = encB + (size_t)ch * 8192 + boff;
    #pragma unroll
    for (int nt = 0; nt < 16; ++nt) {
      short8 bf = *(const short8*)(bp + nt * 512);
      acc[nt] = __builtin_amdgcn_mfma_f32_16x16x32_bf16(af, bf, acc[nt], 0, 0, 0);
    }
  }
  den += __shfl_xor(den, 16);
  den += __shfl_xor(den, 32);                // full row-sum at every kg lane
  // ---- epilogue: /den, layernorm, write bf16 ----
  float gl[16], cl[16];
  #pragma unroll
  for (int nt = 0; nt < 16; ++nt) { gl[nt] = gamma[nt * 16 + m]; cl[nt] = beta[nt * 16 + m]; }
  const int q = lane >> 4;
  #pragma unroll
  for (int r = 0; r < 4; ++r) {
    const int row = q * 4 + r;               // local row held by this lane's C-frag
    float dnr = __shfl(den, row);            // den lives at lane==row (m==row, kg=0 group ok: all kg copies equal)
    float rd = 1.0f / dnr;
    float h[16];
    float sm = 0.0f, sq = 0.0f;
    #pragma unroll
    for (int nt = 0; nt < 16; ++nt) {
      h[nt] = acc[nt][r] * rd;
      sm += h[nt]; sq += h[nt] * h[nt];
    }
    #pragma unroll
    for (int off = 1; off < 16; off <<= 1) {  // reduce across the 16 col-lanes of this quad
      sm += __shfl_xor(sm, off);
      sq += __shfl_xor(sq, off);
    }
    float mean = sm * (1.0f / 256.0f);
    float var = sq * (1.0f / 256.0f) - mean * mean;
    float rstd = rsqrtf(var + 1e-6f);
    ushort_t* dst = hidden_bf + ((size_t)(base + tl * 16 + row)) * DD + m;
    #pragma unroll
    for (int nt = 0; nt < 16; ++nt)
      dst[nt * 16] = f2bfu((h[nt] - mean) * rstd * gl[nt] + cl[nt]);
  }
}

// ---------------- Kernel E: MFMA generator (concat-K GEMM + fused relu/dot/softplus) ----------------
__global__ __launch_bounds__(256) void k_gen(
    const ushort_t* __restrict__ noise_bf, const ushort_t* __restrict__ hidden_bf,
    const ushort_t* __restrict__ wcat, const float* __restrict__ wout,
    const float* __restrict__ bout, float* __restrict__ out)
{
  const int tid = threadIdx.x;
  const int lane = tid & 63, wv = tid >> 6;
  const int tile = blockIdx.x * 4 + wv;      // 0..1023, 16 rows each
  const int m = lane & 15, kg = lane >> 4;
  const int r = tile * 16 + m;               // A-frag row
  floatx4 acc[16];
  #pragma unroll
  for (int nt = 0; nt < 16; ++nt) acc[nt] = (floatx4){0.f, 0.f, 0.f, 0.f};
  const ushort_t* __restrict__ arow_n = noise_bf + (size_t)r * DD;
  const ushort_t* __restrict__ arow_h = hidden_bf + (size_t)r * DD;
  #pragma unroll
  for (int ks = 0; ks < 16; ++ks) {          // K = 512 in steps of 32
    const int k0 = ks * 32;
    const ushort_t* ap = (k0 < 256) ? (arow_n + k0 + kg * 8)
                                    : (arow_h + (k0 - 256) + kg * 8);
    short8 af = *(const short8*)ap;
    const ushort_t* bp = wcat + k0 + kg * 8 + (size_t)m * 512;
    #pragma unroll
    for (int nt = 0; nt < 16; ++nt) {
      short8 bf = *(const short8*)(bp + (size_t)nt * 8192);   // col = nt*16+m, stride 16*512
      acc[nt] = __builtin_amdgcn_mfma_f32_16x16x32_bf16(af, bf, acc[nt], 0, 0, 0);
    }
  }
  // epilogue: out[row] = softplus( sum_c relu(X[row,c]) * wout[c] + bo )
  float wo_l[16];
  #pragma unroll
  for (int nt = 0; nt < 16; ++nt) wo_l[nt] = wout[nt * 16 + m];
  const float bo = bout[0];
  const int q = lane >> 4;
  #pragma unroll
  for (int r4 = 0; r4 < 4; ++r4) {
    float p = 0.0f;
    #pragma unroll
    for (int nt = 0; nt < 16; ++nt) p += fmaxf(acc[nt][r4], 0.0f) * wo_l[nt];
    #pragma unroll
    for (int off = 1; off < 16; off <<= 1) p += __shfl_xor(p, off);
    if (m == 0) {
      float x = p + bo;
      float sp = (x > 15.0f) ? x : log1pf(__expf(x));
      out[tile * 16 + q * 4 + r4] = sp;
    }
  }
}

extern "C" void kernel_launch(void* const* d_in, const int* in_sizes, int n_in,
                              void* d_out, int out_size, void* d_ws, size_t ws_size,
                              hipStream_t stream) {
  const int*   etype = (const int*)d_in[0];
  const float* etime = (const float*)d_in[1];
  const float* embw  = (const float*)d_in[2];
  const float* gatew = (const float*)d_in[3];
  const float* gateb = (const float*)d_in[4];
  const float* kerw  = (const float*)d_in[5];
  const float* kerb  = (const float*)d_in[6];
  const float* gamma = (const float*)d_in[7];
  const float* beta  = (const float*)d_in[8];
  const float* wi    = (const float*)d_in[9];   // gen_input_w
  const float* wn    = (const float*)d_in[10];  // gen_noise_w
  const float* wo    = (const float*)d_in[11];  // gen_out_w
  const float* bo    = (const float*)d_in[12];  // gen_out_b
  const float* noise = (const float*)d_in[13];
  float* out = (float*)d_out;

  char* w8 = (char*)d_ws;
  float* t_arr  = (float*)(w8);
  float* invls2 = (float*)(w8 + 65536);
  float* l_arr  = (float*)(w8 + 131072);
  float* invs   = (float*)(w8 + 196608);
  ushort_t* enc_bf    = (ushort_t*)(w8 + 262144);                 // 8 MB
  ushort_t* hidden_bf = (ushort_t*)(w8 + 262144 + 8388608);       // 8 MB
  ushort_t* noise_bf  = (ushort_t*)(w8 + 262144 + 2 * 8388608);   // 8 MB
  ushort_t* wcat      = (ushort_t*)(w8 + 262144 + 3 * 8388608);   // 256 KB

  k_cast<<<4224, 256, 0, stream>>>(noise, wn, wi, noise_bf, wcat);
  k_prep_params<<<BD * LD, 256, 0, stream>>>(etype, etime, embw, gatew, gateb,
                                             kerw, kerb, t_arr, invls2, l_arr, invs);
  k_prep_enc<<<512, 256, 0, stream>>>(t_arr, enc_bf);
  k_attn<<<256, 256, 0, stream>>>(enc_bf, t_arr, invls2, l_arr, invs,
                                  gamma, beta, hidden_bf);
  k_gen<<<256, 256, 0, stream>>>(noise_bf, hidden_bf, wcat, wo, bo, out);
}

// Round 5
// 221.238 us; speedup vs baseline: 1.8450x; 1.0774x over previous
//
#include <hip/hip_runtime.h>
#include <hip/hip_bf16.h>

#define BD 8
#define LD 2048
#define DD 256

typedef unsigned short ushort_t;
typedef __attribute__((ext_vector_type(8))) short short8;
typedef __attribute__((ext_vector_type(4))) float floatx4;

__device__ __forceinline__ float bfu2f(ushort_t u) {
  union { unsigned int i; float f; } v; v.i = ((unsigned int)u) << 16; return v.f;
}
__device__ __forceinline__ ushort_t f2bfu(float x) {
  __hip_bfloat16 h = __float2bfloat16(x);
  return *reinterpret_cast<ushort_t*>(&h);
}

// ---------------- Kernel A: per-TYPE params (only NUM_TYPES+1 = 2 distinct rows) ----------------
// ptable[ty*4+0] = 1/ls^2, +1 = gate l, +2 = 1/s
__global__ __launch_bounds__(256) void k_dots(
    const float* __restrict__ embw, const float* __restrict__ gatew,
    const float* __restrict__ gateb, const float* __restrict__ kerw,
    const float* __restrict__ kerb, float* __restrict__ ptable)
{
  int d = threadIdx.x;
  int lane = d & 63, wvi = d >> 6;
  __shared__ float red[4][3];
  for (int ty = 0; ty < 2; ++ty) {
    float te = embw[ty * DD + d] * 16.0f;   // * sqrt(256)
    float p1 = te * kerw[d];
    float p2 = te * gatew[d];
    float p3 = te * gatew[DD + d];
    #pragma unroll
    for (int off = 32; off > 0; off >>= 1) {
      p1 += __shfl_xor(p1, off);
      p2 += __shfl_xor(p2, off);
      p3 += __shfl_xor(p3, off);
    }
    if (lane == 0) { red[wvi][0] = p1; red[wvi][1] = p2; red[wvi][2] = p3; }
    __syncthreads();
    if (d == 0) {
      float s1 = red[0][0] + red[1][0] + red[2][0] + red[3][0] + kerb[0];
      float s2 = red[0][1] + red[1][1] + red[2][1] + red[3][1] + gateb[0];
      float s3 = red[0][2] + red[1][2] + red[2][2] + red[3][2] + gateb[1];
      float z = 0.2f * s1;
      float sp = (z > 15.0f) ? z : log1pf(__expf(z));
      float ls = 5.0f * sp;                  // softplus(0.2x)/0.2
      ptable[ty * 4 + 0] = 1.0f / (ls * ls);
      ptable[ty * 4 + 1] = 1.0f / (1.0f + __expf(-s2));
      float s = 1.0f / (1.0f + __expf(-s3));
      ptable[ty * 4 + 2] = 1.0f / s;
    }
    __syncthreads();
  }
}

// ---------------- Kernel B: temporal encoding, bf16, B-fragment-native layout ----------------
// enc_bf[b][ch][d][jj]  (ch = j>>5, jj = j&31): 16B at (d*32 + kg*8) is one B-frag slice.
__global__ __launch_bounds__(256) void k_prep_enc(
    const float* __restrict__ etime, ushort_t* __restrict__ enc_bf)
{
  int bk = blockIdx.x;            // 0..511 : b = bk>>6, ch = bk&63
  int d = threadIdx.x;
  __shared__ float ts[32];
  if (d < 32) ts[d] = etime[(bk >> 6) * LD + (bk & 63) * 32 + d];
  __syncthreads();
  float freq = __expf(-0.07195578416f * (float)d);   // 10000^(-2d/256)
  unsigned int pk[16];
  #pragma unroll
  for (int j2 = 0; j2 < 16; ++j2) {
    float a0 = ts[2 * j2] * freq;
    float a1 = ts[2 * j2 + 1] * freq;
    float v0 = (d & 1) ? cosf(a0) : sinf(a0);
    float v1 = (d & 1) ? cosf(a1) : sinf(a1);
    pk[j2] = (unsigned int)f2bfu(v0) | ((unsigned int)f2bfu(v1) << 16);
  }
  uint4* dst = (uint4*)(enc_bf + ((size_t)bk * 256 + d) * 32);
  dst[0] = make_uint4(pk[0], pk[1], pk[2], pk[3]);
  dst[1] = make_uint4(pk[4], pk[5], pk[6], pk[7]);
  dst[2] = make_uint4(pk[8], pk[9], pk[10], pk[11]);
  dst[3] = make_uint4(pk[12], pk[13], pk[14], pk[15]);
}

// ---------------- Kernel C: cast noise + concat weights to bf16 ----------------
__global__ __launch_bounds__(256) void k_cast(
    const float* __restrict__ noise, const float* __restrict__ wn,
    const float* __restrict__ wi, ushort_t* __restrict__ noise_bf,
    ushort_t* __restrict__ wcat)
{
  int idx = blockIdx.x * 256 + threadIdx.x;     // float4 index
  if (idx < 1048576) {
    float4 f = ((const float4*)noise)[idx];
    ushort4 u;
    u.x = f2bfu(f.x); u.y = f2bfu(f.y); u.z = f2bfu(f.z); u.w = f2bfu(f.w);
    *(ushort4*)(noise_bf + (size_t)idx * 4) = u;
  } else {
    int p = idx - 1048576;                      // 0..32767
    int c = p >> 7;
    int k = (p & 127) * 4;
    const float* src = (k < 256) ? (wn + c * 256 + k) : (wi + c * 256 + (k - 256));
    float4 f = *(const float4*)src;
    ushort4 u;
    u.x = f2bfu(f.x); u.y = f2bfu(f.y); u.z = f2bfu(f.z); u.w = f2bfu(f.w);
    *(ushort4*)(wcat + (size_t)c * 512 + k) = u;
  }
}

// ---------------- Kernel D: MFMA causal gated attention + layernorm ----------------
// 1024 blocks = one 16-row tile each (big tiles dispatched first); 4 waves K-split the
// j-chunk range (ch ≡ wv mod 4); partials combined via LDS; wave 0 does the epilogue.
__global__ __launch_bounds__(256) void k_attn(
    const ushort_t* __restrict__ enc_bf, const float* __restrict__ etime,
    const int* __restrict__ etype, const float* __restrict__ ptable,
    const float* __restrict__ gamma, const float* __restrict__ beta,
    ushort_t* __restrict__ hidden_bf)
{
  __shared__ floatx4 lds_acc[16 * 3 * 64];   // 48 KB, [nt][wv-1][lane] -> conflict-free
  __shared__ float lds_den[3 * 64];
  const int tid = threadIdx.x;
  const int lane = tid & 63, wv = tid >> 6;
  const int bk = blockIdx.x;
  const int b = bk & 7;
  const int tl = 127 - (bk >> 3);            // big tiles first, interleaved across b
  const int base = b * LD;
  const int m = lane & 15, kg = lane >> 4;
  const int i = tl * 16 + m;                 // this lane's A-row
  const float ti = etime[base + i];
  const int ty = etype[base + i];
  const float il = ptable[ty * 4 + 0];
  const float ll = ptable[ty * 4 + 1];
  const float is2 = 2.0f * ptable[ty * 4 + 2];
  floatx4 acc[16];
  #pragma unroll
  for (int nt = 0; nt < 16; ++nt) acc[nt] = (floatx4){0.f, 0.f, 0.f, 0.f};
  float den = 0.0f;
  const int nch = tl / 2 + 1;
  const ushort_t* __restrict__ encB = enc_bf + (size_t)(b * 64) * 8192;
  const int boff = m * 32 + kg * 8;          // B-frag lane offset within a chunk
  for (int ch = wv; ch < nch; ch += 4) {
    const int j0 = ch * 32 + kg * 8;
    float4 tja = *(const float4*)(etime + base + j0);
    float4 tjb = *(const float4*)(etime + base + j0 + 4);
    float tj[8] = {tja.x, tja.y, tja.z, tja.w, tjb.x, tjb.y, tjb.z, tjb.w};
    short8 af;
    #pragma unroll
    for (int v = 0; v < 8; ++v) {
      float dt = fabsf(ti - tj[v]);
      float sk = __expf(-dt * dt * il);
      float rg = __builtin_amdgcn_rcpf(__expf((dt * 0.005f - ll) * is2) + 1.0f);
      float w = __expf(sk * (1.5f - rg));    // exp(sk * gate), gate = 1.5 - 1/(e^{2z}+1)
      w = (j0 + v <= i) ? w : 0.0f;          // causal mask
      ushort_t ub = f2bfu(w);
      af[v] = (short)ub;
      den += bfu2f(ub);                      // denominator consistent with bf16 numerator
    }
    const ushort_t* bp = encB + (size_t)ch * 8192 + boff;
    #pragma unroll
    for (int nt = 0; nt < 16; ++nt) {
      short8 bf = *(const short8*)(bp + nt * 512);
      acc[nt] = __builtin_amdgcn_mfma_f32_16x16x32_bf16(af, bf, acc[nt], 0, 0, 0);
    }
  }
  den += __shfl_xor(den, 16);
  den += __shfl_xor(den, 32);                // per-row partial at every kg lane
  if (wv != 0) {
    #pragma unroll
    for (int nt = 0; nt < 16; ++nt) lds_acc[(nt * 3 + (wv - 1)) * 64 + lane] = acc[nt];
    lds_den[(wv - 1) * 64 + lane] = den;
  }
  __syncthreads();
  if (wv == 0) {
    #pragma unroll
    for (int nt = 0; nt < 16; ++nt) {
      acc[nt] += lds_acc[(nt * 3 + 0) * 64 + lane];
      acc[nt] += lds_acc[(nt * 3 + 1) * 64 + lane];
      acc[nt] += lds_acc[(nt * 3 + 2) * 64 + lane];
    }
    den += lds_den[0 * 64 + lane] + lds_den[1 * 64 + lane] + lds_den[2 * 64 + lane];
    // ---- epilogue: /den, layernorm, write bf16 ----
    float gl[16], cl[16];
    #pragma unroll
    for (int nt = 0; nt < 16; ++nt) { gl[nt] = gamma[nt * 16 + m]; cl[nt] = beta[nt * 16 + m]; }
    const int q = lane >> 4;
    #pragma unroll
    for (int r = 0; r < 4; ++r) {
      const int row = q * 4 + r;             // local row held by this lane's C-frag
      float dnr = __shfl(den, row);          // den for row lives at lane==row
      float rd = 1.0f / dnr;
      float h[16];
      float sm = 0.0f, sq = 0.0f;
      #pragma unroll
      for (int nt = 0; nt < 16; ++nt) {
        h[nt] = acc[nt][r] * rd;
        sm += h[nt]; sq += h[nt] * h[nt];
      }
      #pragma unroll
      for (int off = 1; off < 16; off <<= 1) {
        sm += __shfl_xor(sm, off);
        sq += __shfl_xor(sq, off);
      }
      float mean = sm * (1.0f / 256.0f);
      float var = sq * (1.0f / 256.0f) - mean * mean;
      float rstd = rsqrtf(var + 1e-6f);
      ushort_t* dst = hidden_bf + ((size_t)(base + tl * 16 + row)) * DD + m;
      #pragma unroll
      for (int nt = 0; nt < 16; ++nt)
        dst[nt * 16] = f2bfu((h[nt] - mean) * rstd * gl[nt] + cl[nt]);
    }
  }
}

// ---------------- Kernel E: MFMA generator, K-split (noise-half / hidden-half) ----------------
__global__ __launch_bounds__(256) void k_gen(
    const ushort_t* __restrict__ noise_bf, const ushort_t* __restrict__ hidden_bf,
    const ushort_t* __restrict__ wcat, const float* __restrict__ wout,
    const float* __restrict__ bout, float* __restrict__ out)
{
  __shared__ floatx4 lds_acc[16 * 2 * 64];   // 32 KB, [nt][slot][lane]
  const int tid = threadIdx.x;
  const int lane = tid & 63, wv = tid >> 6;
  const int s = wv >> 1, kh = wv & 1;        // slot (which tile), K-half
  const int tile = blockIdx.x * 2 + s;       // 0..1023, 16 rows each
  const int m = lane & 15, kg = lane >> 4;
  const int r = tile * 16 + m;               // A-frag row
  floatx4 acc[16];
  #pragma unroll
  for (int nt = 0; nt < 16; ++nt) acc[nt] = (floatx4){0.f, 0.f, 0.f, 0.f};
  const ushort_t* __restrict__ arow =
      ((kh == 0) ? noise_bf : hidden_bf) + (size_t)r * DD;
  #pragma unroll
  for (int ks = 0; ks < 8; ++ks) {           // this wave's K = 256 in steps of 32
    const int k0g = kh * 256 + ks * 32;      // global k into wcat
    short8 af = *(const short8*)(arow + ks * 32 + kg * 8);
    const ushort_t* bp = wcat + k0g + kg * 8 + (size_t)m * 512;
    #pragma unroll
    for (int nt = 0; nt < 16; ++nt) {
      short8 bf = *(const short8*)(bp + (size_t)nt * 8192);   // col = nt*16+m
      acc[nt] = __builtin_amdgcn_mfma_f32_16x16x32_bf16(af, bf, acc[nt], 0, 0, 0);
    }
  }
  if (kh == 1) {
    #pragma unroll
    for (int nt = 0; nt < 16; ++nt) lds_acc[(nt * 2 + s) * 64 + lane] = acc[nt];
  }
  __syncthreads();
  if (kh == 0) {
    #pragma unroll
    for (int nt = 0; nt < 16; ++nt) acc[nt] += lds_acc[(nt * 2 + s) * 64 + lane];
    // epilogue: out[row] = softplus( sum_c relu(X[row,c]) * wout[c] + bo )
    float wo_l[16];
    #pragma unroll
    for (int nt = 0; nt < 16; ++nt) wo_l[nt] = wout[nt * 16 + m];
    const float bo = bout[0];
    const int q = lane >> 4;
    #pragma unroll
    for (int r4 = 0; r4 < 4; ++r4) {
      float p = 0.0f;
      #pragma unroll
      for (int nt = 0; nt < 16; ++nt) p += fmaxf(acc[nt][r4], 0.0f) * wo_l[nt];
      #pragma unroll
      for (int off = 1; off < 16; off <<= 1) p += __shfl_xor(p, off);
      if (m == 0) {
        float x = p + bo;
        float sp = (x > 15.0f) ? x : log1pf(__expf(x));
        out[tile * 16 + q * 4 + r4] = sp;
      }
    }
  }
}

extern "C" void kernel_launch(void* const* d_in, const int* in_sizes, int n_in,
                              void* d_out, int out_size, void* d_ws, size_t ws_size,
                              hipStream_t stream) {
  const int*   etype = (const int*)d_in[0];
  const float* etime = (const float*)d_in[1];
  const float* embw  = (const float*)d_in[2];
  const float* gatew = (const float*)d_in[3];
  const float* gateb = (const float*)d_in[4];
  const float* kerw  = (const float*)d_in[5];
  const float* kerb  = (const float*)d_in[6];
  const float* gamma = (const float*)d_in[7];
  const float* beta  = (const float*)d_in[8];
  const float* wi    = (const float*)d_in[9];   // gen_input_w
  const float* wn    = (const float*)d_in[10];  // gen_noise_w
  const float* wo    = (const float*)d_in[11];  // gen_out_w
  const float* bo    = (const float*)d_in[12];  // gen_out_b
  const float* noise = (const float*)d_in[13];
  float* out = (float*)d_out;

  char* w8 = (char*)d_ws;
  float* ptable       = (float*)(w8);                             // 32 B
  ushort_t* enc_bf    = (ushort_t*)(w8 + 262144);                 // 8 MB
  ushort_t* hidden_bf = (ushort_t*)(w8 + 262144 + 8388608);       // 8 MB
  ushort_t* noise_bf  = (ushort_t*)(w8 + 262144 + 2 * 8388608);   // 8 MB
  ushort_t* wcat      = (ushort_t*)(w8 + 262144 + 3 * 8388608);   // 256 KB

  k_dots<<<1, 256, 0, stream>>>(embw, gatew, gateb, kerw, kerb, ptable);
  k_cast<<<4224, 256, 0, stream>>>(noise, wn, wi, noise_bf, wcat);
  k_prep_enc<<<512, 256, 0, stream>>>(etime, enc_bf);
  k_attn<<<1024, 256, 0, stream>>>(enc_bf, etime, etype, ptable,
                                   gamma, beta, hidden_bf);
  k_gen<<<512, 256, 0, stream>>>(noise_bf, hidden_bf, wcat, wo, bo, out);
}

// Round 6
// 183.418 us; speedup vs baseline: 2.2254x; 1.2062x over previous
//
#include <hip/hip_runtime.h>
#include <hip/hip_bf16.h>

#define BD 8
#define LD 2048
#define DD 256

typedef unsigned short ushort_t;
typedef __attribute__((ext_vector_type(8))) short short8;
typedef __attribute__((ext_vector_type(4))) float floatx4;

__device__ __forceinline__ float bfu2f(ushort_t u) {
  union { unsigned int i; float f; } v; v.i = ((unsigned int)u) << 16; return v.f;
}
__device__ __forceinline__ ushort_t f2bfu(float x) {
  __hip_bfloat16 h = __float2bfloat16(x);
  return *reinterpret_cast<ushort_t*>(&h);
}

// ---------------- Kernel A: per-TYPE params (only NUM_TYPES+1 = 2 distinct rows) ----------------
// ptable[ty*4+0] = 1/ls^2, +1 = gate l, +2 = 1/s
__global__ __launch_bounds__(256) void k_dots(
    const float* __restrict__ embw, const float* __restrict__ gatew,
    const float* __restrict__ gateb, const float* __restrict__ kerw,
    const float* __restrict__ kerb, float* __restrict__ ptable)
{
  int d = threadIdx.x;
  int lane = d & 63, wvi = d >> 6;
  __shared__ float red[4][3];
  for (int ty = 0; ty < 2; ++ty) {
    float te = embw[ty * DD + d] * 16.0f;   // * sqrt(256)
    float p1 = te * kerw[d];
    float p2 = te * gatew[d];
    float p3 = te * gatew[DD + d];
    #pragma unroll
    for (int off = 32; off > 0; off >>= 1) {
      p1 += __shfl_xor(p1, off);
      p2 += __shfl_xor(p2, off);
      p3 += __shfl_xor(p3, off);
    }
    if (lane == 0) { red[wvi][0] = p1; red[wvi][1] = p2; red[wvi][2] = p3; }
    __syncthreads();
    if (d == 0) {
      float s1 = red[0][0] + red[1][0] + red[2][0] + red[3][0] + kerb[0];
      float s2 = red[0][1] + red[1][1] + red[2][1] + red[3][1] + gateb[0];
      float s3 = red[0][2] + red[1][2] + red[2][2] + red[3][2] + gateb[1];
      float z = 0.2f * s1;
      float sp = (z > 15.0f) ? z : log1pf(__expf(z));
      float ls = 5.0f * sp;                  // softplus(0.2x)/0.2
      ptable[ty * 4 + 0] = 1.0f / (ls * ls);
      ptable[ty * 4 + 1] = 1.0f / (1.0f + __expf(-s2));
      float s = 1.0f / (1.0f + __expf(-s3));
      ptable[ty * 4 + 2] = 1.0f / s;
    }
    __syncthreads();
  }
}

// ---------------- Kernel B: temporal encoding, bf16, B-fragment-native layout ----------------
// enc_bf[b][ch][d][jj]  (ch = j>>5, jj = j&31): 16B at (d*32 + kg*8) is one B-frag slice.
__global__ __launch_bounds__(256) void k_prep_enc(
    const float* __restrict__ etime, ushort_t* __restrict__ enc_bf)
{
  int bk = blockIdx.x;            // 0..511 : b = bk>>6, ch = bk&63
  int d = threadIdx.x;
  __shared__ float ts[32];
  if (d < 32) ts[d] = etime[(bk >> 6) * LD + (bk & 63) * 32 + d];
  __syncthreads();
  float freq = __expf(-0.07195578416f * (float)d);   // 10000^(-2d/256)
  unsigned int pk[16];
  #pragma unroll
  for (int j2 = 0; j2 < 16; ++j2) {
    float a0 = ts[2 * j2] * freq;
    float a1 = ts[2 * j2 + 1] * freq;
    float v0 = (d & 1) ? __cosf(a0) : __sinf(a0);    // hw v_sin/v_cos: ~4 inst vs ~35 libm
    float v1 = (d & 1) ? __cosf(a1) : __sinf(a1);
    pk[j2] = (unsigned int)f2bfu(v0) | ((unsigned int)f2bfu(v1) << 16);
  }
  uint4* dst = (uint4*)(enc_bf + ((size_t)bk * 256 + d) * 32);
  dst[0] = make_uint4(pk[0], pk[1], pk[2], pk[3]);
  dst[1] = make_uint4(pk[4], pk[5], pk[6], pk[7]);
  dst[2] = make_uint4(pk[8], pk[9], pk[10], pk[11]);
  dst[3] = make_uint4(pk[12], pk[13], pk[14], pk[15]);
}

// ---------------- Kernel C: cast noise + concat weights to bf16 ----------------
__global__ __launch_bounds__(256) void k_cast(
    const float* __restrict__ noise, const float* __restrict__ wn,
    const float* __restrict__ wi, ushort_t* __restrict__ noise_bf,
    ushort_t* __restrict__ wcat)
{
  int idx = blockIdx.x * 256 + threadIdx.x;     // float4 index
  if (idx < 1048576) {
    float4 f = ((const float4*)noise)[idx];
    ushort4 u;
    u.x = f2bfu(f.x); u.y = f2bfu(f.y); u.z = f2bfu(f.z); u.w = f2bfu(f.w);
    *(ushort4*)(noise_bf + (size_t)idx * 4) = u;
  } else {
    int p = idx - 1048576;                      // 0..32767
    int c = p >> 7;
    int k = (p & 127) * 4;
    const float* src = (k < 256) ? (wn + c * 256 + k) : (wi + c * 256 + (k - 256));
    float4 f = *(const float4*)src;
    ushort4 u;
    u.x = f2bfu(f.x); u.y = f2bfu(f.y); u.z = f2bfu(f.z); u.w = f2bfu(f.w);
    *(ushort4*)(wcat + (size_t)c * 512 + k) = u;
  }
}

// ---------------- Kernel D: MFMA causal gated attention + layernorm ----------------
// 1024 blocks = one 16-row tile each (big first); 4 waves K-split (ch ≡ wv mod 4).
// B-frags prefetched 8-at-a-time (loads issued before the exp chain); partials
// combined via two-stage 24.6 KB LDS (6 blocks/CU); wave 0 does the epilogue.
__global__ __launch_bounds__(256, 4) void k_attn(
    const ushort_t* __restrict__ enc_bf, const float* __restrict__ etime,
    const int* __restrict__ etype, const float* __restrict__ ptable,
    const float* __restrict__ gamma, const float* __restrict__ beta,
    ushort_t* __restrict__ hidden_bf)
{
  __shared__ floatx4 lds_acc[8 * 3 * 64];    // 24 KB, [nt8][wv-1][lane]
  __shared__ float lds_den[3 * 64];
  const int tid = threadIdx.x;
  const int lane = tid & 63, wv = tid >> 6;
  const int bk = blockIdx.x;
  const int b = bk & 7;
  const int tl = 127 - (bk >> 3);            // big tiles first, interleaved across b
  const int base = b * LD;
  const int m = lane & 15, kg = lane >> 4;
  const int i = tl * 16 + m;                 // this lane's A-row
  const float ti = etime[base + i];
  const int ty = etype[base + i];
  const float il = ptable[ty * 4 + 0];
  const float ll = ptable[ty * 4 + 1];
  const float is2 = 2.0f * ptable[ty * 4 + 2];
  floatx4 acc[16];
  #pragma unroll
  for (int nt = 0; nt < 16; ++nt) acc[nt] = (floatx4){0.f, 0.f, 0.f, 0.f};
  float den = 0.0f;
  const int nch = tl / 2 + 1;
  const ushort_t* __restrict__ encB = enc_bf + (size_t)(b * 64) * 8192;
  const int boff = m * 32 + kg * 8;          // B-frag lane offset within a chunk
  for (int ch = wv; ch < nch; ch += 4) {
    const ushort_t* bp = encB + (size_t)ch * 8192 + boff;
    short8 bfr[8];
    #pragma unroll
    for (int nt = 0; nt < 8; ++nt) bfr[nt] = *(const short8*)(bp + nt * 512);   // 8 in flight
    const int j0 = ch * 32 + kg * 8;
    float4 tja = *(const float4*)(etime + base + j0);
    float4 tjb = *(const float4*)(etime + base + j0 + 4);
    float tj[8] = {tja.x, tja.y, tja.z, tja.w, tjb.x, tjb.y, tjb.z, tjb.w};
    short8 af;
    #pragma unroll
    for (int v = 0; v < 8; ++v) {           // ~400 cyc of VALU hides the load latency
      float dt = fabsf(ti - tj[v]);
      float sk = __expf(-dt * dt * il);
      float rg = __builtin_amdgcn_rcpf(__expf((dt * 0.005f - ll) * is2) + 1.0f);
      float w = __expf(sk * (1.5f - rg));    // exp(sk * gate), gate = 1.5 - 1/(e^{2z}+1)
      w = (j0 + v <= i) ? w : 0.0f;          // causal mask
      ushort_t ub = f2bfu(w);
      af[v] = (short)ub;
      den += bfu2f(ub);                      // denominator consistent with bf16 numerator
    }
    #pragma unroll
    for (int nt = 0; nt < 8; ++nt)
      acc[nt] = __builtin_amdgcn_mfma_f32_16x16x32_bf16(af, bfr[nt], acc[nt], 0, 0, 0);
    #pragma unroll
    for (int nt = 0; nt < 8; ++nt) bfr[nt] = *(const short8*)(bp + (nt + 8) * 512);
    #pragma unroll
    for (int nt = 0; nt < 8; ++nt)
      acc[nt + 8] = __builtin_amdgcn_mfma_f32_16x16x32_bf16(af, bfr[nt], acc[nt + 8], 0, 0, 0);
  }
  den += __shfl_xor(den, 16);
  den += __shfl_xor(den, 32);                // per-row partial at every kg lane
  // ---- two-stage cross-wave combine (8 nt per stage keeps LDS at 24.6 KB) ----
  if (wv != 0) {
    #pragma unroll
    for (int nt = 0; nt < 8; ++nt) lds_acc[(nt * 3 + (wv - 1)) * 64 + lane] = acc[nt];
    lds_den[(wv - 1) * 64 + lane] = den;
  }
  __syncthreads();
  if (wv == 0) {
    #pragma unroll
    for (int nt = 0; nt < 8; ++nt) {
      acc[nt] += lds_acc[(nt * 3 + 0) * 64 + lane];
      acc[nt] += lds_acc[(nt * 3 + 1) * 64 + lane];
      acc[nt] += lds_acc[(nt * 3 + 2) * 64 + lane];
    }
    den += lds_den[0 * 64 + lane] + lds_den[1 * 64 + lane] + lds_den[2 * 64 + lane];
  }
  __syncthreads();
  if (wv != 0) {
    #pragma unroll
    for (int nt = 0; nt < 8; ++nt) lds_acc[(nt * 3 + (wv - 1)) * 64 + lane] = acc[nt + 8];
  }
  __syncthreads();
  if (wv == 0) {
    #pragma unroll
    for (int nt = 0; nt < 8; ++nt) {
      acc[nt + 8] += lds_acc[(nt * 3 + 0) * 64 + lane];
      acc[nt + 8] += lds_acc[(nt * 3 + 1) * 64 + lane];
      acc[nt + 8] += lds_acc[(nt * 3 + 2) * 64 + lane];
    }
    // ---- epilogue: /den, layernorm, write bf16 ----
    float gl[16], cl[16];
    #pragma unroll
    for (int nt = 0; nt < 16; ++nt) { gl[nt] = gamma[nt * 16 + m]; cl[nt] = beta[nt * 16 + m]; }
    const int q = lane >> 4;
    #pragma unroll
    for (int r = 0; r < 4; ++r) {
      const int row = q * 4 + r;             // local row held by this lane's C-frag
      float dnr = __shfl(den, row);          // den for row lives at lane==row
      float rd = 1.0f / dnr;
      float h[16];
      float sm = 0.0f, sq = 0.0f;
      #pragma unroll
      for (int nt = 0; nt < 16; ++nt) {
        h[nt] = acc[nt][r] * rd;
        sm += h[nt]; sq += h[nt] * h[nt];
      }
      #pragma unroll
      for (int off = 1; off < 16; off <<= 1) {
        sm += __shfl_xor(sm, off);
        sq += __shfl_xor(sq, off);
      }
      float mean = sm * (1.0f / 256.0f);
      float var = sq * (1.0f / 256.0f) - mean * mean;
      float rstd = rsqrtf(var + 1e-6f);
      ushort_t* dst = hidden_bf + ((size_t)(base + tl * 16 + row)) * DD + m;
      #pragma unroll
      for (int nt = 0; nt < 16; ++nt)
        dst[nt * 16] = f2bfu((h[nt] - mean) * rstd * gl[nt] + cl[nt]);
    }
  }
}

// ---------------- Kernel E: MFMA generator, 4-way K-split, two-stage LDS combine ----------------
__global__ __launch_bounds__(256, 4) void k_gen(
    const ushort_t* __restrict__ noise_bf, const ushort_t* __restrict__ hidden_bf,
    const ushort_t* __restrict__ wcat, const float* __restrict__ wout,
    const float* __restrict__ bout, float* __restrict__ out)
{
  __shared__ floatx4 lds_acc[8 * 3 * 64];    // 24 KB
  const int tid = threadIdx.x;
  const int lane = tid & 63, wv = tid >> 6;
  const int tile = blockIdx.x;               // 0..1023, 16 rows each
  const int m = lane & 15, kg = lane >> 4;
  const int r = tile * 16 + m;               // A-frag row
  floatx4 acc[16];
  #pragma unroll
  for (int nt = 0; nt < 16; ++nt) acc[nt] = (floatx4){0.f, 0.f, 0.f, 0.f};
  // wave wv handles global k in [wv*128, wv*128+128): wv 0,1 -> noise; 2,3 -> hidden
  const ushort_t* __restrict__ arow =
      ((wv < 2) ? noise_bf : hidden_bf) + (size_t)r * DD + (wv & 1) * 128;
  #pragma unroll
  for (int ks = 0; ks < 4; ++ks) {           // this wave's K = 128 in steps of 32
    short8 af = *(const short8*)(arow + ks * 32 + kg * 8);
    const ushort_t* bp = wcat + (wv * 128 + ks * 32) + kg * 8 + (size_t)m * 512;
    short8 bfr[8];
    #pragma unroll
    for (int nt = 0; nt < 8; ++nt) bfr[nt] = *(const short8*)(bp + (size_t)nt * 8192);
    #pragma unroll
    for (int nt = 0; nt < 8; ++nt)
      acc[nt] = __builtin_amdgcn_mfma_f32_16x16x32_bf16(af, bfr[nt], acc[nt], 0, 0, 0);
    #pragma unroll
    for (int nt = 0; nt < 8; ++nt) bfr[nt] = *(const short8*)(bp + (size_t)(nt + 8) * 8192);
    #pragma unroll
    for (int nt = 0; nt < 8; ++nt)
      acc[nt + 8] = __builtin_amdgcn_mfma_f32_16x16x32_bf16(af, bfr[nt], acc[nt + 8], 0, 0, 0);
  }
  if (wv != 0) {
    #pragma unroll
    for (int nt = 0; nt < 8; ++nt) lds_acc[(nt * 3 + (wv - 1)) * 64 + lane] = acc[nt];
  }
  __syncthreads();
  if (wv == 0) {
    #pragma unroll
    for (int nt = 0; nt < 8; ++nt) {
      acc[nt] += lds_acc[(nt * 3 + 0) * 64 + lane];
      acc[nt] += lds_acc[(nt * 3 + 1) * 64 + lane];
      acc[nt] += lds_acc[(nt * 3 + 2) * 64 + lane];
    }
  }
  __syncthreads();
  if (wv != 0) {
    #pragma unroll
    for (int nt = 0; nt < 8; ++nt) lds_acc[(nt * 3 + (wv - 1)) * 64 + lane] = acc[nt + 8];
  }
  __syncthreads();
  if (wv == 0) {
    #pragma unroll
    for (int nt = 0; nt < 8; ++nt) {
      acc[nt + 8] += lds_acc[(nt * 3 + 0) * 64 + lane];
      acc[nt + 8] += lds_acc[(nt * 3 + 1) * 64 + lane];
      acc[nt + 8] += lds_acc[(nt * 3 + 2) * 64 + lane];
    }
    // epilogue: out[row] = softplus( sum_c relu(X[row,c]) * wout[c] + bo )
    float wo_l[16];
    #pragma unroll
    for (int nt = 0; nt < 16; ++nt) wo_l[nt] = wout[nt * 16 + m];
    const float bo = bout[0];
    const int q = lane >> 4;
    #pragma unroll
    for (int r4 = 0; r4 < 4; ++r4) {
      float p = 0.0f;
      #pragma unroll
      for (int nt = 0; nt < 16; ++nt) p += fmaxf(acc[nt][r4], 0.0f) * wo_l[nt];
      #pragma unroll
      for (int off = 1; off < 16; off <<= 1) p += __shfl_xor(p, off);
      if (m == 0) {
        float x = p + bo;
        float sp = (x > 15.0f) ? x : log1pf(__expf(x));
        out[tile * 16 + q * 4 + r4] = sp;
      }
    }
  }
}

extern "C" void kernel_launch(void* const* d_in, const int* in_sizes, int n_in,
                              void* d_out, int out_size, void* d_ws, size_t ws_size,
                              hipStream_t stream) {
  const int*   etype = (const int*)d_in[0];
  const float* etime = (const float*)d_in[1];
  const float* embw  = (const float*)d_in[2];
  const float* gatew = (const float*)d_in[3];
  const float* gateb = (const float*)d_in[4];
  const float* kerw  = (const float*)d_in[5];
  const float* kerb  = (const float*)d_in[6];
  const float* gamma = (const float*)d_in[7];
  const float* beta  = (const float*)d_in[8];
  const float* wi    = (const float*)d_in[9];   // gen_input_w
  const float* wn    = (const float*)d_in[10];  // gen_noise_w
  const float* wo    = (const float*)d_in[11];  // gen_out_w
  const float* bo    = (const float*)d_in[12];  // gen_out_b
  const float* noise = (const float*)d_in[13];
  float* out = (float*)d_out;

  char* w8 = (char*)d_ws;
  float* ptable       = (float*)(w8);                             // 32 B
  ushort_t* enc_bf    = (ushort_t*)(w8 + 262144);                 // 8 MB
  ushort_t* hidden_bf = (ushort_t*)(w8 + 262144 + 8388608);       // 8 MB
  ushort_t* noise_bf  = (ushort_t*)(w8 + 262144 + 2 * 8388608);   // 8 MB
  ushort_t* wcat      = (ushort_t*)(w8 + 262144 + 3 * 8388608);   // 256 KB

  k_dots<<<1, 256, 0, stream>>>(embw, gatew, gateb, kerw, kerb, ptable);
  k_cast<<<4224, 256, 0, stream>>>(noise, wn, wi, noise_bf, wcat);
  k_prep_enc<<<512, 256, 0, stream>>>(etime, enc_bf);
  k_attn<<<1024, 256, 0, stream>>>(enc_bf, etime, etype, ptable,
                                   gamma, beta, hidden_bf);
  k_gen<<<1024, 256, 0, stream>>>(noise_bf, hidden_bf, wcat, wo, bo, out);
}

// Round 7
// 162.297 us; speedup vs baseline: 2.5150x; 1.1301x over previous
//
#include <hip/hip_runtime.h>
#include <hip/hip_bf16.h>

#define BD 8
#define LD 2048
#define DD 256

typedef unsigned short ushort_t;
typedef __attribute__((ext_vector_type(8))) short short8;
typedef __attribute__((ext_vector_type(4))) float floatx4;

__device__ __forceinline__ ushort_t f2bfu(float x) {
  __hip_bfloat16 h = __float2bfloat16(x);
  return *reinterpret_cast<ushort_t*>(&h);
}

// async global->LDS DMA, 16 B per lane; LDS dest must be wave-uniform base (+lane*16 implicit)
__device__ __forceinline__ void dma16(const ushort_t* g, ushort_t* l) {
  __builtin_amdgcn_global_load_lds(
      (const __attribute__((address_space(1))) unsigned int*)g,
      (__attribute__((address_space(3))) unsigned int*)l,
      16, 0, 0);
}

// accurate sin/cos for args up to ~200 rad: single Cody-Waite step (fma-exact), then hw trig
__device__ __forceinline__ float sin_acc(float a) {
  float k = rintf(a * 0.15915494f);
  float r = __builtin_fmaf(-k, 6.2831855f, a);
  r = __builtin_fmaf(-k, -1.7484555e-7f, r);
  return __sinf(r);
}
__device__ __forceinline__ float cos_acc(float a) {
  float k = rintf(a * 0.15915494f);
  float r = __builtin_fmaf(-k, 6.2831855f, a);
  r = __builtin_fmaf(-k, -1.7484555e-7f, r);
  return __cosf(r);
}

// ---------------- Kernel A: per-TYPE params (only NUM_TYPES+1 = 2 distinct rows) ----------------
__global__ __launch_bounds__(256) void k_dots(
    const float* __restrict__ embw, const float* __restrict__ gatew,
    const float* __restrict__ gateb, const float* __restrict__ kerw,
    const float* __restrict__ kerb, float* __restrict__ ptable)
{
  int d = threadIdx.x;
  int lane = d & 63, wvi = d >> 6;
  __shared__ float red[4][3];
  for (int ty = 0; ty < 2; ++ty) {
    float te = embw[ty * DD + d] * 16.0f;   // * sqrt(256)
    float p1 = te * kerw[d];
    float p2 = te * gatew[d];
    float p3 = te * gatew[DD + d];
    #pragma unroll
    for (int off = 32; off > 0; off >>= 1) {
      p1 += __shfl_xor(p1, off);
      p2 += __shfl_xor(p2, off);
      p3 += __shfl_xor(p3, off);
    }
    if (lane == 0) { red[wvi][0] = p1; red[wvi][1] = p2; red[wvi][2] = p3; }
    __syncthreads();
    if (d == 0) {
      float s1 = red[0][0] + red[1][0] + red[2][0] + red[3][0] + kerb[0];
      float s2 = red[0][1] + red[1][1] + red[2][1] + red[3][1] + gateb[0];
      float s3 = red[0][2] + red[1][2] + red[2][2] + red[3][2] + gateb[1];
      float z = 0.2f * s1;
      float sp = (z > 15.0f) ? z : log1pf(__expf(z));
      float ls = 5.0f * sp;                  // softplus(0.2x)/0.2
      ptable[ty * 4 + 0] = 1.0f / (ls * ls);
      ptable[ty * 4 + 1] = 1.0f / (1.0f + __expf(-s2));
      float s = 1.0f / (1.0f + __expf(-s3));
      ptable[ty * 4 + 2] = 1.0f / s;
    }
    __syncthreads();
  }
}

// ---------------- Kernel B: temporal encoding, bf16, B-frag-native, coalesced stores ----------------
// enc_bf[b][ch][d][jj]; flat uint4 index within tile = jblk*256 + tid -> d=jblk*64+tid/4, jj=(tid%4)*8
__global__ __launch_bounds__(256) void k_prep_enc(
    const float* __restrict__ etime, ushort_t* __restrict__ enc_bf)
{
  int bk = blockIdx.x;            // 0..511 : b = bk>>6, ch = bk&63
  int tid = threadIdx.x;
  __shared__ float ts[32];
  if (tid < 32) ts[tid] = etime[(bk >> 6) * LD + (bk & 63) * 32 + tid];
  __syncthreads();
  uint4* dst = (uint4*)(enc_bf + (size_t)bk * 8192);
  const int jb = (tid & 3) * 8;
  #pragma unroll
  for (int jblk = 0; jblk < 4; ++jblk) {
    int d = jblk * 64 + (tid >> 2);
    float freq = __expf(-0.07195578416f * (float)d);   // 10000^(-2d/256)
    unsigned int pk[4];
    #pragma unroll
    for (int p = 0; p < 4; ++p) {
      float a0 = ts[jb + 2 * p] * freq;
      float a1 = ts[jb + 2 * p + 1] * freq;
      float v0 = (d & 1) ? cos_acc(a0) : sin_acc(a0);
      float v1 = (d & 1) ? cos_acc(a1) : sin_acc(a1);
      pk[p] = (unsigned int)f2bfu(v0) | ((unsigned int)f2bfu(v1) << 16);
    }
    dst[jblk * 256 + tid] = make_uint4(pk[0], pk[1], pk[2], pk[3]);
  }
}

// ---------------- Kernel C: cast noise + concat weights to bf16 ----------------
__global__ __launch_bounds__(256) void k_cast(
    const float* __restrict__ noise, const float* __restrict__ wn,
    const float* __restrict__ wi, ushort_t* __restrict__ noise_bf,
    ushort_t* __restrict__ wcat)
{
  int idx = blockIdx.x * 256 + threadIdx.x;     // float4 index
  if (idx < 1048576) {
    float4 f = ((const float4*)noise)[idx];
    ushort4 u;
    u.x = f2bfu(f.x); u.y = f2bfu(f.y); u.z = f2bfu(f.z); u.w = f2bfu(f.w);
    *(ushort4*)(noise_bf + (size_t)idx * 4) = u;
  } else {
    int p = idx - 1048576;                      // 0..32767
    int c = p >> 7;
    int k = (p & 127) * 4;
    const float* src = (k < 256) ? (wn + c * 256 + k) : (wi + c * 256 + (k - 256));
    float4 f = *(const float4*)src;
    ushort4 u;
    u.x = f2bfu(f.x); u.y = f2bfu(f.y); u.z = f2bfu(f.z); u.w = f2bfu(f.w);
    *(ushort4*)(wcat + (size_t)c * 512 + k) = u;
  }
}

// ---------------- Kernel D: MFMA causal gated attention + layernorm ----------------
// 1024 blocks = one 16-row tile (big first); 4 waves K-split (ch ≡ wv mod 4).
// Per iter: 16x global_load_lds DMA the full 16 KB enc chunk into this wave's LDS
// region (zero VGPR cost, 16 outstanding), weight/exp chain overlaps the DMA,
// then vmcnt(0) + 16x(ds_read_b128 + MFMA). Softmax denominator is DROPPED:
// LayerNorm is scale-invariant (eps effect <= 1e-5 relative).
__global__ __launch_bounds__(256, 4) void k_attn(
    const ushort_t* __restrict__ enc_bf, const float* __restrict__ etime,
    const int* __restrict__ etype, const float* __restrict__ ptable,
    const float* __restrict__ gamma, const float* __restrict__ beta,
    ushort_t* __restrict__ hidden_bf)
{
  __shared__ __align__(16) ushort_t stage[4][8192];   // 64 KB; per-wave DMA staging, aliased for combine
  const int tid = threadIdx.x;
  const int lane = tid & 63, wv = tid >> 6;
  const int bk = blockIdx.x;
  const int b = bk & 7;
  const int tl = 127 - (bk >> 3);            // big tiles first, interleaved across b
  const int base = b * LD;
  const int m = lane & 15, kg = lane >> 4;
  const int i = tl * 16 + m;                 // this lane's A-row
  const float ti = etime[base + i];
  const int ty = etype[base + i];
  const float il = ptable[ty * 4 + 0];
  const float ll = ptable[ty * 4 + 1];
  const float is2 = 2.0f * ptable[ty * 4 + 2];
  floatx4 acc[16];
  #pragma unroll
  for (int nt = 0; nt < 16; ++nt) acc[nt] = (floatx4){0.f, 0.f, 0.f, 0.f};
  const int nch = tl / 2 + 1;
  const ushort_t* __restrict__ encC = enc_bf + (size_t)(b * 64) * 8192;
  const int boff = m * 32 + kg * 8;          // frag lane offset (ushorts) within a 1 KB frag
  ushort_t* mybuf = &stage[wv][0];
  for (int ch = wv; ch < nch; ch += 4) {
    const int j0 = ch * 32 + kg * 8;
    float4 tja = *(const float4*)(etime + base + j0);     // issued BEFORE the DMAs
    float4 tjb = *(const float4*)(etime + base + j0 + 4);
    __builtin_amdgcn_s_waitcnt(0xC07F);      // lgkmcnt(0): prior ds_reads retired before overwrite
    const ushort_t* gsrc = encC + (size_t)ch * 8192 + lane * 8;
    #pragma unroll
    for (int nt = 0; nt < 16; ++nt)
      dma16(gsrc + nt * 512, mybuf + nt * 512);
    float tj[8] = {tja.x, tja.y, tja.z, tja.w, tjb.x, tjb.y, tjb.z, tjb.w};
    short8 af;
    #pragma unroll
    for (int v = 0; v < 8; ++v) {            // ~500 cyc of VALU — the DMA completes underneath
      float dt = fabsf(ti - tj[v]);
      float sk = __expf(-dt * dt * il);
      float rg = __builtin_amdgcn_rcpf(__expf((dt * 0.005f - ll) * is2) + 1.0f);
      float w = __expf(sk * (1.5f - rg));    // exp(sk * gate), gate = 1.5 - 1/(e^{2z}+1)
      w = (j0 + v <= i) ? w : 0.0f;          // causal mask
      af[v] = (short)f2bfu(w);
    }
    __builtin_amdgcn_s_waitcnt(0x0F70);      // vmcnt(0): DMA done
    #pragma unroll
    for (int nt = 0; nt < 16; ++nt) {
      short8 bf = *(const short8*)(mybuf + nt * 512 + boff);
      acc[nt] = __builtin_amdgcn_mfma_f32_16x16x32_bf16(af, bf, acc[nt], 0, 0, 0);
    }
  }
  // ---- cross-wave combine (stage aliased as 48 KB float4 buffer) ----
  __syncthreads();                           // all waves done with their staging regions
  floatx4* lds_acc = (floatx4*)&stage[0][0];
  if (wv != 0) {
    #pragma unroll
    for (int nt = 0; nt < 16; ++nt) lds_acc[(nt * 3 + (wv - 1)) * 64 + lane] = acc[nt];
  }
  __syncthreads();
  if (wv == 0) {
    #pragma unroll
    for (int nt = 0; nt < 16; ++nt) {
      acc[nt] += lds_acc[(nt * 3 + 0) * 64 + lane];
      acc[nt] += lds_acc[(nt * 3 + 1) * 64 + lane];
      acc[nt] += lds_acc[(nt * 3 + 2) * 64 + lane];
    }
    // ---- epilogue: layernorm on RAW weighted sums (softmax div absorbed), write bf16 ----
    float gl[16], cl[16];
    #pragma unroll
    for (int nt = 0; nt < 16; ++nt) { gl[nt] = gamma[nt * 16 + m]; cl[nt] = beta[nt * 16 + m]; }
    const int q = lane >> 4;
    #pragma unroll
    for (int r = 0; r < 4; ++r) {
      float h[16];
      float sm = 0.0f, sq = 0.0f;
      #pragma unroll
      for (int nt = 0; nt < 16; ++nt) {
        h[nt] = acc[nt][r];
        sm += h[nt]; sq += h[nt] * h[nt];
      }
      #pragma unroll
      for (int off = 1; off < 16; off <<= 1) {
        sm += __shfl_xor(sm, off);
        sq += __shfl_xor(sq, off);
      }
      float mean = sm * (1.0f / 256.0f);
      float var = sq * (1.0f / 256.0f) - mean * mean;
      float rstd = rsqrtf(var + 1e-6f);
      const int row = q * 4 + r;
      ushort_t* dst = hidden_bf + ((size_t)(base + tl * 16 + row)) * DD + m;
      #pragma unroll
      for (int nt = 0; nt < 16; ++nt)
        dst[nt * 16] = f2bfu((h[nt] - mean) * rstd * gl[nt] + cl[nt]);
    }
  }
}

// ---------------- Kernel E: MFMA generator: 512 blocks x 32 rows; wave = col-quarter ----------------
// Wave owns cols [wv*64, wv*64+64) with FULL K=512 (no K-combine); 2 row-tiles share B-frags.
__global__ __launch_bounds__(256) void k_gen(
    const ushort_t* __restrict__ noise_bf, const ushort_t* __restrict__ hidden_bf,
    const ushort_t* __restrict__ wcat, const float* __restrict__ wout,
    const float* __restrict__ bout, float* __restrict__ out)
{
  __shared__ float pbuf[4][2][16];
  const int tid = threadIdx.x;
  const int lane = tid & 63, wv = tid >> 6;  // wv = col-quarter
  const int m = lane & 15, kg = lane >> 4;
  const int r0 = blockIdx.x * 32 + m;
  const ushort_t* __restrict__ an0 = noise_bf + (size_t)r0 * DD;
  const ushort_t* __restrict__ an1 = noise_bf + (size_t)(r0 + 16) * DD;
  const ushort_t* __restrict__ ah0 = hidden_bf + (size_t)r0 * DD;
  const ushort_t* __restrict__ ah1 = hidden_bf + (size_t)(r0 + 16) * DD;
  floatx4 acc[2][4];
  #pragma unroll
  for (int t = 0; t < 2; ++t)
    #pragma unroll
    for (int n = 0; n < 4; ++n) acc[t][n] = (floatx4){0.f, 0.f, 0.f, 0.f};
  const ushort_t* __restrict__ bbase = wcat + ((size_t)(wv * 4) * 16 + m) * 512 + kg * 8;
  #pragma unroll
  for (int ks = 0; ks < 16; ++ks) {          // K = 512 in steps of 32
    const int koff = (ks & 7) * 32 + kg * 8;
    short8 a0 = *(const short8*)(((ks < 8) ? an0 : ah0) + koff);
    short8 a1 = *(const short8*)(((ks < 8) ? an1 : ah1) + koff);
    const ushort_t* bp = bbase + ks * 32;
    #pragma unroll
    for (int n = 0; n < 4; ++n) {
      short8 bf = *(const short8*)(bp + (size_t)n * 8192);   // col = (wv*4+n)*16+m
      acc[0][n] = __builtin_amdgcn_mfma_f32_16x16x32_bf16(a0, bf, acc[0][n], 0, 0, 0);
      acc[1][n] = __builtin_amdgcn_mfma_f32_16x16x32_bf16(a1, bf, acc[1][n], 0, 0, 0);
    }
  }
  // epilogue: partial head-dot per col-quarter, combine across waves in LDS
  float wo_l[4];
  #pragma unroll
  for (int n = 0; n < 4; ++n) wo_l[n] = wout[(wv * 4 + n) * 16 + m];
  #pragma unroll
  for (int t = 0; t < 2; ++t) {
    #pragma unroll
    for (int r4 = 0; r4 < 4; ++r4) {
      float p = 0.0f;
      #pragma unroll
      for (int n = 0; n < 4; ++n) p += fmaxf(acc[t][n][r4], 0.0f) * wo_l[n];
      #pragma unroll
      for (int off = 1; off < 16; off <<= 1) p += __shfl_xor(p, off);
      if (m == 0) pbuf[wv][t][kg * 4 + r4] = p;
    }
  }
  __syncthreads();
  if (tid < 32) {
    int t = tid >> 4, rr = tid & 15;
    float x = pbuf[0][t][rr] + pbuf[1][t][rr] + pbuf[2][t][rr] + pbuf[3][t][rr] + bout[0];
    float sp = (x > 15.0f) ? x : log1pf(__expf(x));
    out[blockIdx.x * 32 + t * 16 + rr] = sp;
  }
}

extern "C" void kernel_launch(void* const* d_in, const int* in_sizes, int n_in,
                              void* d_out, int out_size, void* d_ws, size_t ws_size,
                              hipStream_t stream) {
  const int*   etype = (const int*)d_in[0];
  const float* etime = (const float*)d_in[1];
  const float* embw  = (const float*)d_in[2];
  const float* gatew = (const float*)d_in[3];
  const float* gateb = (const float*)d_in[4];
  const float* kerw  = (const float*)d_in[5];
  const float* kerb  = (const float*)d_in[6];
  const float* gamma = (const float*)d_in[7];
  const float* beta  = (const float*)d_in[8];
  const float* wi    = (const float*)d_in[9];   // gen_input_w
  const float* wn    = (const float*)d_in[10];  // gen_noise_w
  const float* wo    = (const float*)d_in[11];  // gen_out_w
  const float* bo    = (const float*)d_in[12];  // gen_out_b
  const float* noise = (const float*)d_in[13];
  float* out = (float*)d_out;

  char* w8 = (char*)d_ws;
  float* ptable       = (float*)(w8);                             // 32 B
  ushort_t* enc_bf    = (ushort_t*)(w8 + 262144);                 // 8 MB
  ushort_t* hidden_bf = (ushort_t*)(w8 + 262144 + 8388608);       // 8 MB
  ushort_t* noise_bf  = (ushort_t*)(w8 + 262144 + 2 * 8388608);   // 8 MB
  ushort_t* wcat      = (ushort_t*)(w8 + 262144 + 3 * 8388608);   // 256 KB

  k_dots<<<1, 256, 0, stream>>>(embw, gatew, gateb, kerw, kerb, ptable);
  k_prep_enc<<<512, 256, 0, stream>>>(etime, enc_bf);
  k_cast<<<4224, 256, 0, stream>>>(noise, wn, wi, noise_bf, wcat);
  k_attn<<<1024, 256, 0, stream>>>(enc_bf, etime, etype, ptable,
                                   gamma, beta, hidden_bf);
  k_gen<<<512, 256, 0, stream>>>(noise_bf, hidden_bf, wcat, wo, bo, out);
}